// Round 2
// baseline (1621.718 us; speedup 1.0000x reference)
//
#include <hip/hip_runtime.h>

#define DTC 0.01f

typedef __attribute__((ext_vector_type(8))) short short8;
typedef __attribute__((ext_vector_type(4))) float floatx4;

#if __has_builtin(__builtin_amdgcn_exp2f)
#define EXP2F(x) __builtin_amdgcn_exp2f(x)
#else
#define EXP2F(x) exp2f(x)
#endif
#if __has_builtin(__builtin_amdgcn_rcpf)
#define RCPF(x) __builtin_amdgcn_rcpf(x)
#else
#define RCPF(x) (1.0f / (x))
#endif

__device__ __forceinline__ unsigned f2bf(float f) {
    unsigned u = __float_as_uint(f);
    u += 0x7FFFu + ((u >> 16) & 1u);
    return u >> 16;
}
__device__ __forceinline__ float sigm(float x) {
    float e = EXP2F(-1.44269504089f * x);
    return RCPF(1.0f + e);
}
__device__ __forceinline__ float tanh_f(float x) {
    float e = EXP2F(2.88539008178f * x);   // e^{2x}
    return 1.0f - 2.0f * RCPF(e + 1.0f);
}

// byte stride 144 = 16*9 (odd multiple of 16B): il*144 mod 128 walks all 8
// 16B chunk positions -> near-uniform bank spread for b128 A-frag reads.
#define U0S 72
#define U1S 72

// 512 threads = 8 waves = 2/SIMD. Wave pair (w, w+4) duplicates the MFMAs
// (cheap) and splits the transcendental cell update by rows: w -> regs {0,1},
// w+4 -> regs {2,3}. s-state lives in registers as s^T (never in LDS).
__global__ __launch_bounds__(512, 2) void lstm_mfma(
    const float* __restrict__ x,    const float* __restrict__ s0,
    const float* __restrict__ W_ih0,const float* __restrict__ W_hh0,
    const float* __restrict__ b_ih0,const float* __restrict__ b_hh0,
    const float* __restrict__ W_ih1,const float* __restrict__ W_hh1,
    const float* __restrict__ b_ih1,const float* __restrict__ b_hh1,
    const float* __restrict__ fc_W, const float* __restrict__ fc_b,
    const int* __restrict__ nsp,    float* __restrict__ out, int B)
{
    __shared__ unsigned short U0[16 * U0S];   // h_a(t), bf16, [row m][hid 0..63]
    __shared__ unsigned short U1[16 * U1S];   // h_b(t), bf16

    const int ns   = nsp[0];
    const int tid  = threadIdx.x;
    const int lane = tid & 63;
    const int wave = tid >> 6;       // 0..7
    const int wq   = wave & 3;       // gate n-tile group (shared by pair)
    const int r0   = (wave >> 2) * 2;// this wave's cell regs: r0, r0+1
    const int il   = lane & 15;
    const int quad = lane >> 4;
    const int bb   = blockIdx.x * 16;

    float* cal = out + (size_t)B * ns * 8;
    float* res = cal + ns;

    if (blockIdx.x == 0)
        for (int t = tid; t < ns; t += 512) cal[t] = t * DTC;

    for (int i = tid; i < 16 * U0S; i += 512) U0[i] = 0;
    for (int i = tid; i < 16 * U1S; i += 512) U1[i] = 0;

    // ---- register-resident B-fragments (constant over time) ----
    // gate j lives at n = 64*j + 16*wq + il -> one wave's MFMA output holds
    // complete (i,f,g,o) quadruples for hidden [16wq, 16wq+16).
    short8 B0[4][3], B1[4][4], FA[2];
    floatx4 bias0[4];
    float bias1[4];
    for (int j = 0; j < 4; ++j) {
        const int n = 64 * j + 16 * wq + il;
        for (int kk = 0; kk < 3; ++kk) {        // G0: K = [h_a(64) | s(8) | 0(24)]
            short8 f;
            #pragma unroll
            for (int jj = 0; jj < 8; ++jj) {
                int k = 32 * kk + 8 * quad + jj;
                float w;
                if (k < 64)      w = W_hh0[n * 64 + k];
                else if (k < 72) w = W_ih0[n * 16 + 8 + (k - 64)];
                else             w = 0.0f;
                f[jj] = (short)f2bf(w);
            }
            B0[j][kk] = f;
        }
        for (int kk = 0; kk < 4; ++kk) {        // G1: K = [h_a(64) | h_b(64)]
            short8 f;
            #pragma unroll
            for (int jj = 0; jj < 8; ++jj) {
                int k = 32 * kk + 8 * quad + jj;
                float w = (k < 64) ? W_ih1[n * 64 + k] : W_hh1[n * 64 + (k - 64)];
                f[jj] = (short)f2bf(w);
            }
            B1[j][kk] = f;
        }
        float bcol = b_ih0[n] + b_hh0[n];       // fold constant xin into bias0
        floatx4 bv;
        #pragma unroll
        for (int reg = 0; reg < 4; ++reg) {
            int m = 4 * quad + reg;
            float acc = bcol;
            for (int k = 0; k < 8; ++k)
                acc += x[(bb + m) * 8 + k] * W_ih0[n * 16 + k];
            bv[reg] = acc;
        }
        bias0[j] = bv;
        bias1[j] = b_ih1[n] + b_hh1[n];
    }
    // FC head as A-operand: A[p][k] = fc_W[p][k] (p<8, rows 8..15 zero).
    // so^T = A * h_b^T ; supplying the h_b A-frag as src1 IS h_b^T in B-layout.
    for (int kk = 0; kk < 2; ++kk) {
        short8 f;
        #pragma unroll
        for (int jj = 0; jj < 8; ++jj) {
            int k = 32 * kk + 8 * quad + jj;
            float w = (il < 8) ? fc_W[il * 64 + k] : 0.0f;
            f[jj] = (short)f2bf(w);
        }
        FA[kk] = f;
    }
    floatx4 biasT;                               // C-init: fc_b[row p], quads 0,1
    #pragma unroll
    for (int reg = 0; reg < 4; ++reg)
        biasT[reg] = (quad < 2) ? fc_b[4 * quad + reg] : 0.0f;

    // ---- state ----
    float cA[2] = {0, 0}, cB[2] = {0, 0};
    floatx4 sT;                                  // s^T: lane(il,q<2) = s[il][4q+reg]
    #pragma unroll
    for (int reg = 0; reg < 4; ++reg)
        sT[reg] = (quad < 2) ? s0[(bb + il) * 8 + 4 * quad + reg] : 0.0f;
    unsigned pk0 = f2bf(sT[0]) | (f2bf(sT[1]) << 16);
    unsigned pk1 = f2bf(sT[2]) | (f2bf(sT[3]) << 16);
    __syncthreads();

    const int iidx = 16 * wq + il;   // hidden index owned for cell updates

    #pragma unroll 1
    for (int t = 0; ; ++t) {
        // top reads: h_a(t-1) and h_b(t-1)
        short8 a00 = *(const short8*)&U0[il * U0S + 0  + 8 * quad];
        short8 a01 = *(const short8*)&U0[il * U0S + 32 + 8 * quad];
        short8 a12 = *(const short8*)&U1[il * U1S + 0  + 8 * quad];
        short8 a13 = *(const short8*)&U1[il * U1S + 32 + 8 * quad];

        // FC head for step t-1 (reuses a12/a13), s(t) = s(t-1) + dt*so
        if (t > 0) {
            floatx4 so = biasT;
            so = __builtin_amdgcn_mfma_f32_16x16x32_bf16(FA[1], a13, so, 0, 0, 0);
            so = __builtin_amdgcn_mfma_f32_16x16x32_bf16(FA[0], a12, so, 0, 0, 0);
            #pragma unroll
            for (int reg = 0; reg < 4; ++reg) sT[reg] += so[reg] * DTC;
            pk0 = f2bf(sT[0]) | (f2bf(sT[1]) << 16);
            pk1 = f2bf(sT[2]) | (f2bf(sT[3]) << 16);
            if (wave == 0 && quad < 2) {
                size_t o = ((size_t)(bb + il) * ns + (t - 1)) * 8 + 4 * quad;
                *(floatx4*)(out + o) = sT;
                *(floatx4*)(res + o) = so;
            }
        }
        if (t == ns) break;

        // a02 (s in A-layout) from registers: quad0 needs s[il][0..7];
        // upper half comes from the quad1 lane via one shuffle.
        int sh0 = __shfl((int)pk0, (lane + 16) & 63, 64);
        int sh1 = __shfl((int)pk1, (lane + 16) & 63, 64);
        union { int i[4]; short8 s8; } ua;
        ua.i[0] = (quad == 0) ? (int)pk0 : 0;
        ua.i[1] = (quad == 0) ? (int)pk1 : 0;
        ua.i[2] = (quad == 0) ? sh0 : 0;
        ua.i[3] = (quad == 0) ? sh1 : 0;
        short8 a02 = ua.s8;

        __syncthreads();   // A: top reads done before h_a(t) overwrite

        // layer 0
        floatx4 g0[4];
        #pragma unroll
        for (int j = 0; j < 4; ++j) {
            floatx4 acc = bias0[j];
            acc = __builtin_amdgcn_mfma_f32_16x16x32_bf16(a00, B0[j][0], acc, 0, 0, 0);
            acc = __builtin_amdgcn_mfma_f32_16x16x32_bf16(a01, B0[j][1], acc, 0, 0, 0);
            acc = __builtin_amdgcn_mfma_f32_16x16x32_bf16(a02, B0[j][2], acc, 0, 0, 0);
            g0[j] = acc;
        }
        #pragma unroll
        for (int rr = 0; rr < 2; ++rr) {         // this wave's row split
            int reg = r0 + rr;
            float ig = sigm(g0[0][reg]);
            float fg = sigm(g0[1][reg]);
            float gg = tanh_f(g0[2][reg]);
            float og = sigm(g0[3][reg]);
            float c  = fg * cA[rr] + ig * gg;
            cA[rr]   = c;
            U0[(4 * quad + reg) * U0S + iidx] = (unsigned short)f2bf(og * tanh_f(c));
        }
        __syncthreads();   // B: h_a(t) complete

        short8 a10 = *(const short8*)&U0[il * U0S + 0  + 8 * quad];
        short8 a11 = *(const short8*)&U0[il * U0S + 32 + 8 * quad];
        floatx4 g1[4];
        #pragma unroll
        for (int j = 0; j < 4; ++j) {
            floatx4 acc = {bias1[j], bias1[j], bias1[j], bias1[j]};
            acc = __builtin_amdgcn_mfma_f32_16x16x32_bf16(a10, B1[j][0], acc, 0, 0, 0);
            acc = __builtin_amdgcn_mfma_f32_16x16x32_bf16(a11, B1[j][1], acc, 0, 0, 0);
            acc = __builtin_amdgcn_mfma_f32_16x16x32_bf16(a12, B1[j][2], acc, 0, 0, 0);
            acc = __builtin_amdgcn_mfma_f32_16x16x32_bf16(a13, B1[j][3], acc, 0, 0, 0);
            g1[j] = acc;
        }
        #pragma unroll
        for (int rr = 0; rr < 2; ++rr) {
            int reg = r0 + rr;
            float ig = sigm(g1[0][reg]);
            float fg = sigm(g1[1][reg]);
            float gg = tanh_f(g1[2][reg]);
            float og = sigm(g1[3][reg]);
            float c  = fg * cB[rr] + ig * gg;
            cB[rr]   = c;
            U1[(4 * quad + reg) * U1S + iidx] = (unsigned short)f2bf(og * tanh_f(c));
        }
        __syncthreads();   // C: h_b(t) complete before next top reads
    }
}

extern "C" void kernel_launch(void* const* d_in, const int* in_sizes, int n_in,
                              void* d_out, int out_size, void* d_ws, size_t ws_size,
                              hipStream_t stream) {
    const float* x     = (const float*)d_in[0];
    const float* s0    = (const float*)d_in[1];
    const float* W_ih0 = (const float*)d_in[2];
    const float* W_hh0 = (const float*)d_in[3];
    const float* b_ih0 = (const float*)d_in[4];
    const float* b_hh0 = (const float*)d_in[5];
    const float* W_ih1 = (const float*)d_in[6];
    const float* W_hh1 = (const float*)d_in[7];
    const float* b_ih1 = (const float*)d_in[8];
    const float* b_hh1 = (const float*)d_in[9];
    const float* fc_W  = (const float*)d_in[10];
    const float* fc_b  = (const float*)d_in[11];
    const int*   nsp   = (const int*)d_in[12];
    (void)d_ws; (void)ws_size; (void)n_in; (void)out_size;
    int B = in_sizes[0] / 8;          // 4096
    dim3 grid(B / 16), block(512);    // 256 blocks -> 1/CU, 8 waves = 2/SIMD
    hipLaunchKernelGGL(lstm_mfma, grid, block, 0, stream,
        x, s0, W_ih0, W_hh0, b_ih0, b_hh0, W_ih1, W_hh1, b_ih1, b_hh1,
        fc_W, fc_b, nsp, (float*)d_out, B);
}